// Round 3
// baseline (474.255 us; speedup 1.0000x reference)
//
#include <hip/hip_runtime.h>
#include <hip/hip_bf16.h>

#define N_ATOMS 200000
#define N_NBR 10
#define N_MOLS 8000
#define HID 128
#define FDIM 151
#define FEAT 200
#define DFF 512
#define FFN_H 256
#define TASKS 12
#define KX 279      // FDIM + HID
#define K1P 288     // KX padded to multiple of 32
#define XS 296      // LDS stride (bf16 elems) for X tile
#define HS 520      // LDS stride (bf16 elems) for H tile
#define FS 132      // LDS stride (f32 elems) for ffn tile
#define KM 328      // HID + FEAT
#define K3 352      // KM padded to multiple of 32
#define MS 360      // LDS stride for molcat tile
#define MT 32       // atoms kernel M-tile
#define GRID_A 768  // persistent blocks for atoms kernel
#define NTILES (N_ATOMS / MT)   // 6250

typedef __hip_bfloat16 bf16;
typedef __attribute__((ext_vector_type(8))) __bf16 bf16x8;
typedef __attribute__((ext_vector_type(4))) float f32x4;

// LDS-only barrier: drains ds ops but leaves global loads in flight (the
// whole point of the cross-tile prefetch pipeline). All cross-wave data in
// atoms_kernel moves through LDS, so lgkmcnt(0) is sufficient.
#define BAR() do { asm volatile("s_waitcnt lgkmcnt(0)" ::: "memory"); __builtin_amdgcn_s_barrier(); } while (0)

__device__ __forceinline__ float bf2f(bf16 x) { return __bfloat162float(x); }
__device__ __forceinline__ float blo(unsigned w) { union { unsigned u; float f; } c; c.u = w << 16; return c.f; }
__device__ __forceinline__ float bhi(unsigned w) { union { unsigned u; float f; } c; c.u = w & 0xFFFF0000u; return c.f; }

// ---------------- weight prep: transpose + bf16 + K-pad (X layout: [aggr | f_atoms]) ----------------
__global__ void prep_weights_kernel(const float* __restrict__ W1,
                                    const float* __restrict__ W2,
                                    const float* __restrict__ Wf1,
                                    bf16* __restrict__ W1bT,
                                    bf16* __restrict__ W2bT,
                                    bf16* __restrict__ Wf1bT) {
  int idx = blockIdx.x * 256 + threadIdx.x;
  if (idx < DFF * K1P) {                       // W1bT[n][k'], 512x288; k'<128 -> aggr, else f_atoms
    int n = idx / K1P, k = idx - n * K1P;
    float v;
    if (k < HID)      v = W1[(size_t)(FDIM + k) * DFF + n];
    else if (k < KX)  v = W1[(size_t)(k - HID) * DFF + n];
    else              v = 0.f;
    W1bT[idx] = __float2bfloat16(v);
    return;
  }
  idx -= DFF * K1P;
  if (idx < HID * DFF) {                       // W2bT[n][k] = W2[k][n], 128x512
    int n = idx / DFF, k = idx - n * DFF;
    W2bT[idx] = __float2bfloat16(W2[(size_t)k * HID + n]);
    return;
  }
  idx -= HID * DFF;
  if (idx < FFN_H * K3) {                      // Wf1bT[n][k] = Wf1[k][n], 256x352
    int n = idx / K3, k = idx - n * K3;
    float v = (k < KM) ? Wf1[(size_t)k * FFN_H + n] : 0.f;
    Wf1bT[idx] = __float2bfloat16(v);
  }
}

// ---------------- atom_output f32 -> bf16 (halves gather traffic) ----------------
__global__ void conv_ao_kernel(const float* __restrict__ ao, bf16* __restrict__ ao16) {
  const int idx = blockIdx.x * 256 + threadIdx.x;   // exactly N_ATOMS*HID/8 threads
  const float4 v0 = *(const float4*)&ao[(size_t)idx * 8];
  const float4 v1 = *(const float4*)&ao[(size_t)idx * 8 + 4];
  union { bf16 h[8]; uint4 u; } pk;
  pk.h[0] = __float2bfloat16(v0.x); pk.h[1] = __float2bfloat16(v0.y);
  pk.h[2] = __float2bfloat16(v0.z); pk.h[3] = __float2bfloat16(v0.w);
  pk.h[4] = __float2bfloat16(v1.x); pk.h[5] = __float2bfloat16(v1.y);
  pk.h[6] = __float2bfloat16(v1.z); pk.h[7] = __float2bfloat16(v1.w);
  *(uint4*)&ao16[(size_t)idx * 8] = pk.u;
}

// ---------------- fused gather + GEMM1(relu) + GEMM2 + LayerNorm, tile-pipelined ----------------
__global__ __launch_bounds__(512)
void atoms_kernel(const bf16* __restrict__ ao16,
                  const float* __restrict__ f_atoms,
                  const int* __restrict__ a2a,
                  const bf16* __restrict__ W1bT,
                  const float* __restrict__ b1,
                  const bf16* __restrict__ W2bT,
                  const float* __restrict__ b2,
                  const float* __restrict__ gamma,
                  const float* __restrict__ beta,
                  bf16* __restrict__ atom_emb) {
  __shared__ char smem[MT * XS * 2 + MT * HS * 2];   // 18944 + 33280 = 52224 B
  bf16* Xs = (bf16*)smem;                 // [MT][XS]  cols: 0..127 aggr, 128..278 f_atoms, 279..287 pad
  bf16* Hs = (bf16*)(smem + MT * XS * 2); // [MT][HS]
  float* Fs = (float*)(smem + MT * XS * 2); // [MT][FS] overlays Hs (written after all Hs reads)

  const int tid = threadIdx.x;
  const int lane = tid & 63;
  const int w = tid >> 6;
  const int lr = lane & 15;
  const int lk = lane >> 4;
  const int r = tid >> 4, c8 = tid & 15;    // gather mapping: (row, 8-col group)

  // hoisted per-lane constants
  const int n2 = w * 16 + lr;
  const float b2v = b2[n2];
  const int wn = w * 64;
  float4 b1v[4];
#pragma unroll
  for (int ni = 0; ni < 4; ++ni) b1v[ni] = *(const float4*)&b1[wn + ni * 16 + lk * 4];
  const float gam0 = gamma[lane], gam1 = gamma[64 + lane];
  const float bet0 = beta[lane],  bet1 = beta[64 + lane];

  // ---------------- prologue: prefetch tile0 (gather + f_atoms) and a2a(tile1)
  int tile = blockIdx.x;
  int a2ar[N_NBR];
  {
    const int arow = tile * MT + r;
#pragma unroll
    for (int j = 0; j < N_NBR; ++j) a2ar[j] = a2a[arow * N_NBR + j];
  }
  uint4 g[N_NBR];
#pragma unroll
  for (int j = 0; j < N_NBR; ++j)
    g[j] = *(const uint4*)&ao16[(size_t)a2ar[j] * HID + c8 * 8];
  float4 fa0, fa1, fa2;
  {
    const float* fb = &f_atoms[(size_t)tile * MT * FDIM];
    fa0 = *(const float4*)&fb[tid * 4];
    fa1 = *(const float4*)&fb[(tid + 512) * 4];
    if (tid < (MT * FDIM / 4 - 1024)) fa2 = *(const float4*)&fb[(tid + 1024) * 4];
  }
  if (tile + GRID_A < NTILES) {
    const int arow = (tile + GRID_A) * MT + r;
#pragma unroll
    for (int j = 0; j < N_NBR; ++j) a2ar[j] = a2a[arow * N_NBR + j];
  }

  for (; tile < NTILES; tile += GRID_A) {
    const int m0 = tile * MT;
    const bool hn = (tile + GRID_A) < NTILES;

    // ---- A: consume prefetched regs -> Xs
    {
      float s[8];
#pragma unroll
      for (int e = 0; e < 8; ++e) s[e] = 0.f;
#pragma unroll
      for (int j = 0; j < N_NBR; ++j) {
        s[0] += blo(g[j].x); s[1] += bhi(g[j].x);
        s[2] += blo(g[j].y); s[3] += bhi(g[j].y);
        s[4] += blo(g[j].z); s[5] += bhi(g[j].z);
        s[6] += blo(g[j].w); s[7] += bhi(g[j].w);
      }
      union { bf16 h[8]; uint4 u; } pk;
#pragma unroll
      for (int e = 0; e < 8; ++e) pk.h[e] = __float2bfloat16(s[e]);
      *(uint4*)&Xs[r * XS + c8 * 8] = pk.u;
    }
    {
      const float4 ff[3] = { fa0, fa1, fa2 };
#pragma unroll
      for (int p = 0; p < 3; ++p) {
        const int q = tid + p * 512;
        if (p < 2 || tid < (MT * FDIM / 4 - 1024)) {
          const float vf[4] = { ff[p].x, ff[p].y, ff[p].z, ff[p].w };
#pragma unroll
          for (int e = 0; e < 4; ++e) {
            const int flat = q * 4 + e;
            const int rr = flat / FDIM, cc = flat - rr * FDIM;
            Xs[rr * XS + HID + cc] = __float2bfloat16(vf[e]);
          }
        }
      }
    }
    if (tid < MT * (K1P - KX)) {
      const int rr = tid / (K1P - KX), cc = tid - rr * (K1P - KX);
      Xs[rr * XS + KX + cc] = __float2bfloat16(0.f);
    }
    BAR();   // (1) Xs ready

    // ---- C1: issue next-tile f_atoms (in flight across GEMM1+GEMM2)
    if (hn) {
      const float* fb = &f_atoms[(size_t)(tile + GRID_A) * MT * FDIM];
      fa0 = *(const float4*)&fb[tid * 4];
      fa1 = *(const float4*)&fb[(tid + 512) * 4];
      if (tid < (MT * FDIM / 4 - 1024)) fa2 = *(const float4*)&fb[(tid + 1024) * 4];
    }

    // ---- GEMM1: Xs[32x288] @ W1 -> relu -> Hs (bf16); D computed transposed
    {
      f32x4 acc[2][4];
#pragma unroll
      for (int mi = 0; mi < 2; ++mi)
#pragma unroll
        for (int ni = 0; ni < 4; ++ni) acc[mi][ni] = (f32x4)0.f;
      __builtin_amdgcn_s_setprio(1);
#pragma unroll 3
      for (int kk = 0; kk < K1P / 32; ++kk) {
        bf16x8 a[2], b[4];
#pragma unroll
        for (int mi = 0; mi < 2; ++mi)
          a[mi] = *(const bf16x8*)&Xs[(mi * 16 + lr) * XS + kk * 32 + lk * 8];
#pragma unroll
        for (int ni = 0; ni < 4; ++ni)
          b[ni] = *(const bf16x8*)&W1bT[(size_t)(wn + ni * 16 + lr) * K1P + kk * 32 + lk * 8];
#pragma unroll
        for (int mi = 0; mi < 2; ++mi)
#pragma unroll
          for (int ni = 0; ni < 4; ++ni)
            acc[mi][ni] = __builtin_amdgcn_mfma_f32_16x16x32_bf16(b[ni], a[mi], acc[mi][ni], 0, 0, 0);
      }
      __builtin_amdgcn_s_setprio(0);
#pragma unroll
      for (int ni = 0; ni < 4; ++ni) {
        const int nb4 = wn + ni * 16 + lk * 4;
        const float bbf[4] = { b1v[ni].x, b1v[ni].y, b1v[ni].z, b1v[ni].w };
#pragma unroll
        for (int mi = 0; mi < 2; ++mi) {
          union { bf16 h[4]; uint2 u2; } pk;
#pragma unroll
          for (int rr = 0; rr < 4; ++rr) {
            const float h = acc[mi][ni][rr] + bbf[rr];
            pk.h[rr] = __float2bfloat16(h > 0.f ? h : 0.f);
          }
          *(uint2*)&Hs[(mi * 16 + lr) * HS + nb4] = pk.u2;
        }
      }
    }
    BAR();   // (2) Hs ready; Xs free

    // ---- C2: issue next-tile gather (a2a for it already in regs); reload a2a two tiles ahead
    if (hn) {
#pragma unroll
      for (int j = 0; j < N_NBR; ++j)
        g[j] = *(const uint4*)&ao16[(size_t)a2ar[j] * HID + c8 * 8];
      if (tile + 2 * GRID_A < NTILES) {
        const int arow2 = (tile + 2 * GRID_A) * MT + r;
#pragma unroll
        for (int j = 0; j < N_NBR; ++j) a2ar[j] = a2a[arow2 * N_NBR + j];
      }
    }

    // ---- GEMM2: Hs[32x512] @ W2 -> acc2
    f32x4 acc2[2];
    acc2[0] = (f32x4)0.f; acc2[1] = (f32x4)0.f;
    __builtin_amdgcn_s_setprio(1);
#pragma unroll 4
    for (int kk = 0; kk < DFF / 32; ++kk) {
      const bf16x8 bfrag = *(const bf16x8*)&W2bT[(size_t)n2 * DFF + kk * 32 + lk * 8];
#pragma unroll
      for (int mi = 0; mi < 2; ++mi) {
        const bf16x8 afrag = *(const bf16x8*)&Hs[(mi * 16 + lr) * HS + kk * 32 + lk * 8];
        acc2[mi] = __builtin_amdgcn_mfma_f32_16x16x32_bf16(afrag, bfrag, acc2[mi], 0, 0, 0);
      }
    }
    __builtin_amdgcn_s_setprio(0);
    BAR();   // (3) all Hs reads done -> Fs may overwrite

    // ---- E: write f32 pre-LN values into Fs (overlays Hs)
#pragma unroll
    for (int mi = 0; mi < 2; ++mi)
#pragma unroll
      for (int rr = 0; rr < 4; ++rr)
        Fs[(mi * 16 + lk * 4 + rr) * FS + n2] = acc2[mi][rr] + b2v;
    BAR();   // (4) Fs ready

    // ---- F: LayerNorm rows, store atom_emb bf16
#pragma unroll
    for (int i = 0; i < MT / 8; ++i) {
      const int row = w * (MT / 8) + i;
      const float x0 = Fs[row * FS + lane];
      const float x1 = Fs[row * FS + 64 + lane];
      float s = x0 + x1;
      float q = x0 * x0 + x1 * x1;
#pragma unroll
      for (int off = 32; off > 0; off >>= 1) {
        s += __shfl_xor(s, off);
        q += __shfl_xor(q, off);
      }
      const float mu = s * (1.f / 128.f);
      const float var = q * (1.f / 128.f) - mu * mu;
      const float rs = rsqrtf(var + 1e-6f);
      const int atom = m0 + row;
      atom_emb[(size_t)atom * HID + lane] =
          __float2bfloat16(gam0 * ((x0 - mu) * rs) + bet0);
      atom_emb[(size_t)atom * HID + 64 + lane] =
          __float2bfloat16(gam1 * ((x1 - mu) * rs) + bet1);
    }
  }
}

// ---------------- segment mean + concat features -> mol_cat bf16 (16 mols/block, vectorized) ----------------
__global__ __launch_bounds__(256)
void mol_kernel(const bf16* __restrict__ atom_emb,
                const float* __restrict__ features,
                const int* __restrict__ a_scope,
                bf16* __restrict__ mol_cat) {
  const int tid = threadIdx.x;
  const int mi = tid >> 4, c8 = tid & 15;
  const int base = blockIdx.x * 16;
  const int m = base + mi;
  const int start = a_scope[2 * m];
  const int size  = a_scope[2 * m + 1];
  float s[8];
#pragma unroll
  for (int e = 0; e < 8; ++e) s[e] = 0.f;
  for (int a = 0; a < size; ++a) {
    const uint4 u = *(const uint4*)&atom_emb[(size_t)(start + a) * HID + c8 * 8];
    s[0] += blo(u.x); s[1] += bhi(u.x);
    s[2] += blo(u.y); s[3] += bhi(u.y);
    s[4] += blo(u.z); s[5] += bhi(u.z);
    s[6] += blo(u.w); s[7] += bhi(u.w);
  }
  const float inv = 1.f / (float)size;
  union { bf16 h[8]; uint4 u; } pk;
#pragma unroll
  for (int e = 0; e < 8; ++e) pk.h[e] = __float2bfloat16(s[e] * inv);
  *(uint4*)&mol_cat[(size_t)m * K3 + c8 * 8] = pk.u;
  // features f32 -> bf16 (50 float4 per mol)
  for (int q = tid; q < 16 * 50; q += 256) {
    const int mm = q / 50, qq = q - mm * 50;
    const float4 v = *(const float4*)&features[(size_t)(base + mm) * FEAT + qq * 4];
    union { bf16 h[4]; uint2 u2; } pf;
    pf.h[0] = __float2bfloat16(v.x); pf.h[1] = __float2bfloat16(v.y);
    pf.h[2] = __float2bfloat16(v.z); pf.h[3] = __float2bfloat16(v.w);
    *(uint2*)&mol_cat[(size_t)(base + mm) * K3 + HID + qq * 4] = pf.u2;
  }
  // zero pad cols 328..351
  for (int q = tid; q < 16 * (K3 - KM); q += 256) {
    const int mm = q / (K3 - KM), qq = q - mm * (K3 - KM);
    mol_cat[(size_t)(base + mm) * K3 + KM + qq] = __float2bfloat16(0.f);
  }
}

// ---------------- mol FFN layer 1: [8000 x 352] @ [352 x 256] relu ----------------
__global__ __launch_bounds__(512)
void molffn1_kernel(const bf16* __restrict__ mol_cat,
                    const bf16* __restrict__ Wf1bT,
                    const float* __restrict__ bf1,
                    bf16* __restrict__ Hf) {
  __shared__ bf16 As[64 * MS];   // 45 KB
  const int tid = threadIdx.x;
  const int m0 = blockIdx.x * 64;
  for (int idx = tid; idx < 64 * (K3 / 8); idx += 512) {
    int rr = idx / (K3 / 8), qv = idx - rr * (K3 / 8);
    *(uint4*)&As[rr * MS + qv * 8] = *(const uint4*)&mol_cat[(size_t)(m0 + rr) * K3 + qv * 8];
  }
  __syncthreads();
  const int lane = tid & 63, w = tid >> 6;
  const int lr = lane & 15, lk = lane >> 4;
  const int wn = w * 32;
  f32x4 acc[4][2];
#pragma unroll
  for (int mi = 0; mi < 4; ++mi)
#pragma unroll
    for (int ni = 0; ni < 2; ++ni) acc[mi][ni] = (f32x4)0.f;
#pragma unroll 3
  for (int kk = 0; kk < K3 / 32; ++kk) {
    bf16x8 a[4], b[2];
#pragma unroll
    for (int mi = 0; mi < 4; ++mi)
      a[mi] = *(const bf16x8*)&As[(mi * 16 + lr) * MS + kk * 32 + lk * 8];
#pragma unroll
    for (int ni = 0; ni < 2; ++ni)
      b[ni] = *(const bf16x8*)&Wf1bT[(size_t)(wn + ni * 16 + lr) * K3 + kk * 32 + lk * 8];
#pragma unroll
    for (int mi = 0; mi < 4; ++mi)
#pragma unroll
      for (int ni = 0; ni < 2; ++ni)
        acc[mi][ni] = __builtin_amdgcn_mfma_f32_16x16x32_bf16(a[mi], b[ni], acc[mi][ni], 0, 0, 0);
  }
#pragma unroll
  for (int ni = 0; ni < 2; ++ni) {
    const int n = wn + ni * 16 + lr;
    const float bias = bf1[n];
#pragma unroll
    for (int mi = 0; mi < 4; ++mi)
#pragma unroll
      for (int rr = 0; rr < 4; ++rr) {
        const int row = mi * 16 + lk * 4 + rr;
        const float h = acc[mi][ni][rr] + bias;
        Hf[(size_t)(m0 + row) * FFN_H + n] = __float2bfloat16(h > 0.f ? h : 0.f);
      }
  }
}

// ---------------- mol FFN layer 2: [8000 x 256] @ [256 x 12] ----------------
__global__ void molffn2_kernel(const bf16* __restrict__ Hf,
                               const float* __restrict__ Wf2,
                               const float* __restrict__ bias2,
                               float* __restrict__ out) {
  const int gid = blockIdx.x * 256 + threadIdx.x;  // exactly 96000 threads
  const int m = gid / TASKS, t = gid - m * TASKS;
  float s = bias2[t];
  for (int k = 0; k < FFN_H; ++k)
    s += bf2f(Hf[(size_t)m * FFN_H + k]) * Wf2[k * TASKS + t];
  out[gid] = s;
}

extern "C" void kernel_launch(void* const* d_in, const int* in_sizes, int n_in,
                              void* d_out, int out_size, void* d_ws, size_t ws_size,
                              hipStream_t stream) {
  const float* atom_output = (const float*)d_in[0];
  const float* f_atoms     = (const float*)d_in[1];
  const float* features    = (const float*)d_in[2];
  const int*   a2a         = (const int*)d_in[3];
  const int*   a_scope     = (const int*)d_in[4];
  const float* W1   = (const float*)d_in[5];
  const float* b1   = (const float*)d_in[6];
  const float* W2   = (const float*)d_in[7];
  const float* b2   = (const float*)d_in[8];
  const float* gamma = (const float*)d_in[9];
  const float* beta  = (const float*)d_in[10];
  const float* Wf1  = (const float*)d_in[11];
  const float* bf1  = (const float*)d_in[12];
  const float* Wf2  = (const float*)d_in[13];
  const float* bf2v = (const float*)d_in[14];
  float* out = (float*)d_out;

  char* ws = (char*)d_ws;
  size_t off = 0;
  bf16* W1bT  = (bf16*)(ws + off); off += (size_t)DFF * K1P * 2;     // 294912
  bf16* W2bT  = (bf16*)(ws + off); off += (size_t)HID * DFF * 2;     // 131072
  bf16* Wf1bT = (bf16*)(ws + off); off += (size_t)FFN_H * K3 * 2;    // 180224
  bf16* atom_emb = (bf16*)(ws + off); off += (size_t)N_ATOMS * HID * 2; // 51.2 MB
  bf16* mol_cat  = (bf16*)(ws + off); off += (size_t)N_MOLS * K3 * 2;   // 5.6 MB
  bf16* Hf       = (bf16*)(ws + off); off += (size_t)N_MOLS * FFN_H * 2;// 4.1 MB
  bf16* ao16     = (bf16*)(ws + off); off += (size_t)N_ATOMS * HID * 2; // 51.2 MB

  hipLaunchKernelGGL(prep_weights_kernel, dim3(1184), dim3(256), 0, stream,
                     W1, W2, Wf1, W1bT, W2bT, Wf1bT);
  hipLaunchKernelGGL(conv_ao_kernel, dim3(N_ATOMS * HID / 8 / 256), dim3(256), 0, stream,
                     atom_output, ao16);
  hipLaunchKernelGGL(atoms_kernel, dim3(GRID_A), dim3(512), 0, stream,
                     ao16, f_atoms, a2a,
                     W1bT, b1, W2bT, b2, gamma, beta, atom_emb);
  hipLaunchKernelGGL(mol_kernel, dim3(N_MOLS / 16), dim3(256), 0, stream,
                     atom_emb, features, a_scope, mol_cat);
  hipLaunchKernelGGL(molffn1_kernel, dim3(N_MOLS / 64), dim3(512), 0, stream,
                     mol_cat, Wf1bT, bf1, Hf);
  hipLaunchKernelGGL(molffn2_kernel, dim3(N_MOLS * TASKS / 256), dim3(256), 0, stream,
                     Hf, Wf2, bf2v, out);
}

// Round 4
// 374.789 us; speedup vs baseline: 1.2654x; 1.2654x over previous
//
#include <hip/hip_runtime.h>
#include <hip/hip_bf16.h>

#define N_ATOMS 200000
#define N_NBR 10
#define N_MOLS 8000
#define HID 128
#define FDIM 151
#define FEAT 200
#define DFF 512
#define FFN_H 256
#define TASKS 12
#define KX 279      // FDIM + HID
#define K1P 288     // KX padded to multiple of 32
#define XS 296      // LDS stride (bf16 elems) for X tile
#define HS 520      // LDS stride (bf16 elems) for H tile
#define FS 132      // LDS stride (f32 elems) for ffn tile
#define KM 328      // HID + FEAT
#define K3 352      // KM padded to multiple of 32
#define MS 360      // LDS stride for molcat tile
#define MT 32       // atoms kernel M-tile

typedef __hip_bfloat16 bf16;
typedef __attribute__((ext_vector_type(8))) __bf16 bf16x8;
typedef __attribute__((ext_vector_type(4))) float f32x4;

__device__ __forceinline__ float bf2f(bf16 x) { return __bfloat162float(x); }
__device__ __forceinline__ float blo(unsigned w) { union { unsigned u; float f; } c; c.u = w << 16; return c.f; }
__device__ __forceinline__ float bhi(unsigned w) { union { unsigned u; float f; } c; c.u = w & 0xFFFF0000u; return c.f; }

// ---------------- weight prep: transpose + bf16 + K-pad (X layout: [aggr | f_atoms]) ----------------
__global__ void prep_weights_kernel(const float* __restrict__ W1,
                                    const float* __restrict__ W2,
                                    const float* __restrict__ Wf1,
                                    bf16* __restrict__ W1bT,
                                    bf16* __restrict__ W2bT,
                                    bf16* __restrict__ Wf1bT) {
  int idx = blockIdx.x * 256 + threadIdx.x;
  if (idx < DFF * K1P) {                       // W1bT[n][k'], 512x288; k'<128 -> aggr, else f_atoms
    int n = idx / K1P, k = idx - n * K1P;
    float v;
    if (k < HID)      v = W1[(size_t)(FDIM + k) * DFF + n];
    else if (k < KX)  v = W1[(size_t)(k - HID) * DFF + n];
    else              v = 0.f;
    W1bT[idx] = __float2bfloat16(v);
    return;
  }
  idx -= DFF * K1P;
  if (idx < HID * DFF) {                       // W2bT[n][k] = W2[k][n], 128x512
    int n = idx / DFF, k = idx - n * DFF;
    W2bT[idx] = __float2bfloat16(W2[(size_t)k * HID + n]);
    return;
  }
  idx -= HID * DFF;
  if (idx < FFN_H * K3) {                      // Wf1bT[n][k] = Wf1[k][n], 256x352
    int n = idx / K3, k = idx - n * K3;
    float v = (k < KM) ? Wf1[(size_t)k * FFN_H + n] : 0.f;
    Wf1bT[idx] = __float2bfloat16(v);
  }
}

// ---------------- atom_output f32 -> bf16 (halves gather traffic) ----------------
__global__ void conv_ao_kernel(const float* __restrict__ ao, bf16* __restrict__ ao16) {
  const int idx = blockIdx.x * 256 + threadIdx.x;   // exactly N_ATOMS*HID/8 threads
  const float4 v0 = *(const float4*)&ao[(size_t)idx * 8];
  const float4 v1 = *(const float4*)&ao[(size_t)idx * 8 + 4];
  union { bf16 h[8]; uint4 u; } pk;
  pk.h[0] = __float2bfloat16(v0.x); pk.h[1] = __float2bfloat16(v0.y);
  pk.h[2] = __float2bfloat16(v0.z); pk.h[3] = __float2bfloat16(v0.w);
  pk.h[4] = __float2bfloat16(v1.x); pk.h[5] = __float2bfloat16(v1.y);
  pk.h[6] = __float2bfloat16(v1.z); pk.h[7] = __float2bfloat16(v1.w);
  *(uint4*)&ao16[(size_t)idx * 8] = pk.u;
}

// ---------------- standalone neighbor gather-sum: no LDS, no barriers, max occupancy ----------------
__global__ __launch_bounds__(256)
void gather_kernel(const bf16* __restrict__ ao16,
                   const int* __restrict__ a2a,
                   bf16* __restrict__ aggr) {
  const int gid = blockIdx.x * 256 + threadIdx.x;   // exactly N_ATOMS*16 threads
  const int atom = gid >> 4, c8 = gid & 15;
  int idxs[N_NBR];
#pragma unroll
  for (int j = 0; j < N_NBR; ++j) idxs[j] = a2a[atom * N_NBR + j];
  float s[8];
#pragma unroll
  for (int e = 0; e < 8; ++e) s[e] = 0.f;
#pragma unroll
  for (int j = 0; j < N_NBR; ++j) {
    const uint4 u = *(const uint4*)&ao16[(size_t)idxs[j] * HID + c8 * 8];
    s[0] += blo(u.x); s[1] += bhi(u.x);
    s[2] += blo(u.y); s[3] += bhi(u.y);
    s[4] += blo(u.z); s[5] += bhi(u.z);
    s[6] += blo(u.w); s[7] += bhi(u.w);
  }
  union { bf16 h[8]; uint4 u; } pk;
#pragma unroll
  for (int e = 0; e < 8; ++e) pk.h[e] = __float2bfloat16(s[e]);
  *(uint4*)&aggr[(size_t)atom * HID + c8 * 8] = pk.u;
}

// ---------------- fused GEMM1(relu) + GEMM2 + LayerNorm (linear staging only) ----------------
__global__ __launch_bounds__(512)
void atoms_kernel(const bf16* __restrict__ aggr,
                  const float* __restrict__ f_atoms,
                  const bf16* __restrict__ W1bT,
                  const float* __restrict__ b1,
                  const bf16* __restrict__ W2bT,
                  const float* __restrict__ b2,
                  const float* __restrict__ gamma,
                  const float* __restrict__ beta,
                  bf16* __restrict__ atom_emb) {
  __shared__ char smem[MT * XS * 2 + MT * HS * 2];   // 18944 + 33280 = 52224 B
  bf16* Xs = (bf16*)smem;                 // [MT][XS]  cols: 0..127 aggr, 128..278 f_atoms, 279..287 pad
  bf16* Hs = (bf16*)(smem + MT * XS * 2); // [MT][HS]
  float* Fs = (float*)smem;               // [MT][FS] aliases Xs (dead after GEMM1)

  const int tid = threadIdx.x;
  const int m0 = blockIdx.x * MT;
  const int lane = tid & 63;
  const int w = tid >> 6;
  const int lr = lane & 15;
  const int lk = lane >> 4;

  // ---- aggr -> Xs[:, 0:128]  (already bf16: pure 16B copy, one per thread)
  {
    const int r = tid >> 4, c8 = tid & 15;
    *(uint4*)&Xs[r * XS + c8 * 8] = *(const uint4*)&aggr[(size_t)(m0 + r) * HID + c8 * 8];
  }

  // ---- f_atoms -> Xs[:, 128:279]  (tile is contiguous in HBM: flat float4 loads)
  for (int q = tid; q < (MT * FDIM) / 4; q += 512) {   // 1208 float4s
    const float4 v = *(const float4*)&f_atoms[(size_t)m0 * FDIM + q * 4];
    const float vf[4] = { v.x, v.y, v.z, v.w };
#pragma unroll
    for (int e = 0; e < 4; ++e) {
      const int flat = q * 4 + e;
      const int rr = flat / FDIM, cc = flat - rr * FDIM;
      Xs[rr * XS + HID + cc] = __float2bfloat16(vf[e]);
    }
  }
  // ---- zero K-pad cols 279..287
  if (tid < MT * (K1P - KX)) {
    const int rr = tid / (K1P - KX), cc = tid - rr * (K1P - KX);
    Xs[rr * XS + KX + cc] = __float2bfloat16(0.f);
  }
  __syncthreads();

  // ---- GEMM1: Xs[32 x 288] @ W1[288 x 512] -> relu -> Hs (bf16), D computed transposed
  {
    const int wn = w * 64;
    f32x4 acc[2][4];
#pragma unroll
    for (int mi = 0; mi < 2; ++mi)
#pragma unroll
      for (int ni = 0; ni < 4; ++ni) acc[mi][ni] = (f32x4)0.f;
    __builtin_amdgcn_s_setprio(1);
#pragma unroll 3
    for (int kk = 0; kk < K1P / 32; ++kk) {
      bf16x8 a[2], b[4];
#pragma unroll
      for (int mi = 0; mi < 2; ++mi)
        a[mi] = *(const bf16x8*)&Xs[(mi * 16 + lr) * XS + kk * 32 + lk * 8];
#pragma unroll
      for (int ni = 0; ni < 4; ++ni)
        b[ni] = *(const bf16x8*)&W1bT[(size_t)(wn + ni * 16 + lr) * K1P + kk * 32 + lk * 8];
#pragma unroll
      for (int mi = 0; mi < 2; ++mi)
#pragma unroll
        for (int ni = 0; ni < 4; ++ni)   // swapped operands: D row index = n, col index = m
          acc[mi][ni] = __builtin_amdgcn_mfma_f32_16x16x32_bf16(b[ni], a[mi], acc[mi][ni], 0, 0, 0);
    }
    __builtin_amdgcn_s_setprio(0);
    // lane holds n = wn+ni*16+lk*4+{0..3}, m = mi*16+lr  -> pack 4 n, ds_write_b64
#pragma unroll
    for (int ni = 0; ni < 4; ++ni) {
      const int nb4 = wn + ni * 16 + lk * 4;
      const float4 bb = *(const float4*)&b1[nb4];
      const float bbf[4] = { bb.x, bb.y, bb.z, bb.w };
#pragma unroll
      for (int mi = 0; mi < 2; ++mi) {
        union { bf16 h[4]; uint2 u2; } pk;
#pragma unroll
        for (int r = 0; r < 4; ++r) {
          const float h = acc[mi][ni][r] + bbf[r];
          pk.h[r] = __float2bfloat16(h > 0.f ? h : 0.f);
        }
        *(uint2*)&Hs[(mi * 16 + lr) * HS + nb4] = pk.u2;
      }
    }
  }
  __syncthreads();

  // ---- GEMM2: Hs[32 x 512] @ W2[512 x 128] -> +b2 -> Fs (f32)
  {
    const int n2 = w * 16 + lr;
    f32x4 acc2[2];
    acc2[0] = (f32x4)0.f; acc2[1] = (f32x4)0.f;
    __builtin_amdgcn_s_setprio(1);
#pragma unroll 4
    for (int kk = 0; kk < DFF / 32; ++kk) {
      const bf16x8 bfrag = *(const bf16x8*)&W2bT[(size_t)n2 * DFF + kk * 32 + lk * 8];
#pragma unroll
      for (int mi = 0; mi < 2; ++mi) {
        const bf16x8 afrag = *(const bf16x8*)&Hs[(mi * 16 + lr) * HS + kk * 32 + lk * 8];
        acc2[mi] = __builtin_amdgcn_mfma_f32_16x16x32_bf16(afrag, bfrag, acc2[mi], 0, 0, 0);
      }
    }
    __builtin_amdgcn_s_setprio(0);
    const float bias2 = b2[n2];
#pragma unroll
    for (int mi = 0; mi < 2; ++mi)
#pragma unroll
      for (int r = 0; r < 4; ++r) {
        const int row = mi * 16 + lk * 4 + r;
        Fs[row * FS + n2] = acc2[mi][r] + bias2;
      }
  }
  __syncthreads();

  // ---- LayerNorm each of MT rows, write atom_emb bf16
  {
#pragma unroll
    for (int i = 0; i < MT / 8; ++i) {
      const int row = w * (MT / 8) + i;
      const float x0 = Fs[row * FS + lane];
      const float x1 = Fs[row * FS + 64 + lane];
      float s = x0 + x1;
      float q = x0 * x0 + x1 * x1;
#pragma unroll
      for (int off = 32; off > 0; off >>= 1) {
        s += __shfl_xor(s, off);
        q += __shfl_xor(q, off);
      }
      const float mu = s * (1.f / 128.f);
      const float var = q * (1.f / 128.f) - mu * mu;
      const float rs = rsqrtf(var + 1e-6f);
      const int atom = m0 + row;
      atom_emb[(size_t)atom * HID + lane] =
          __float2bfloat16(gamma[lane] * ((x0 - mu) * rs) + beta[lane]);
      atom_emb[(size_t)atom * HID + 64 + lane] =
          __float2bfloat16(gamma[64 + lane] * ((x1 - mu) * rs) + beta[64 + lane]);
    }
  }
}

// ---------------- segment mean + concat features -> mol_cat bf16 (16 mols/block, vectorized) ----------------
__global__ __launch_bounds__(256)
void mol_kernel(const bf16* __restrict__ atom_emb,
                const float* __restrict__ features,
                const int* __restrict__ a_scope,
                bf16* __restrict__ mol_cat) {
  const int tid = threadIdx.x;
  const int mi = tid >> 4, c8 = tid & 15;
  const int base = blockIdx.x * 16;
  const int m = base + mi;
  const int start = a_scope[2 * m];
  const int size  = a_scope[2 * m + 1];
  float s[8];
#pragma unroll
  for (int e = 0; e < 8; ++e) s[e] = 0.f;
  for (int a = 0; a < size; ++a) {
    const uint4 u = *(const uint4*)&atom_emb[(size_t)(start + a) * HID + c8 * 8];
    s[0] += blo(u.x); s[1] += bhi(u.x);
    s[2] += blo(u.y); s[3] += bhi(u.y);
    s[4] += blo(u.z); s[5] += bhi(u.z);
    s[6] += blo(u.w); s[7] += bhi(u.w);
  }
  const float inv = 1.f / (float)size;
  union { bf16 h[8]; uint4 u; } pk;
#pragma unroll
  for (int e = 0; e < 8; ++e) pk.h[e] = __float2bfloat16(s[e] * inv);
  *(uint4*)&mol_cat[(size_t)m * K3 + c8 * 8] = pk.u;
  // features f32 -> bf16 (50 float4 per mol)
  for (int q = tid; q < 16 * 50; q += 256) {
    const int mm = q / 50, qq = q - mm * 50;
    const float4 v = *(const float4*)&features[(size_t)(base + mm) * FEAT + qq * 4];
    union { bf16 h[4]; uint2 u2; } pf;
    pf.h[0] = __float2bfloat16(v.x); pf.h[1] = __float2bfloat16(v.y);
    pf.h[2] = __float2bfloat16(v.z); pf.h[3] = __float2bfloat16(v.w);
    *(uint2*)&mol_cat[(size_t)(base + mm) * K3 + HID + qq * 4] = pf.u2;
  }
  // zero pad cols 328..351
  for (int q = tid; q < 16 * (K3 - KM); q += 256) {
    const int mm = q / (K3 - KM), qq = q - mm * (K3 - KM);
    mol_cat[(size_t)(base + mm) * K3 + KM + qq] = __float2bfloat16(0.f);
  }
}

// ---------------- mol FFN layer 1: [8000 x 352] @ [352 x 256] relu ----------------
__global__ __launch_bounds__(512)
void molffn1_kernel(const bf16* __restrict__ mol_cat,
                    const bf16* __restrict__ Wf1bT,
                    const float* __restrict__ bf1,
                    bf16* __restrict__ Hf) {
  __shared__ bf16 As[64 * MS];   // 45 KB
  const int tid = threadIdx.x;
  const int m0 = blockIdx.x * 64;
  for (int idx = tid; idx < 64 * (K3 / 8); idx += 512) {
    int rr = idx / (K3 / 8), qv = idx - rr * (K3 / 8);
    *(uint4*)&As[rr * MS + qv * 8] = *(const uint4*)&mol_cat[(size_t)(m0 + rr) * K3 + qv * 8];
  }
  __syncthreads();
  const int lane = tid & 63, w = tid >> 6;
  const int lr = lane & 15, lk = lane >> 4;
  const int wn = w * 32;
  f32x4 acc[4][2];
#pragma unroll
  for (int mi = 0; mi < 4; ++mi)
#pragma unroll
    for (int ni = 0; ni < 2; ++ni) acc[mi][ni] = (f32x4)0.f;
#pragma unroll 3
  for (int kk = 0; kk < K3 / 32; ++kk) {
    bf16x8 a[4], b[2];
#pragma unroll
    for (int mi = 0; mi < 4; ++mi)
      a[mi] = *(const bf16x8*)&As[(mi * 16 + lr) * MS + kk * 32 + lk * 8];
#pragma unroll
    for (int ni = 0; ni < 2; ++ni)
      b[ni] = *(const bf16x8*)&Wf1bT[(size_t)(wn + ni * 16 + lr) * K3 + kk * 32 + lk * 8];
#pragma unroll
    for (int mi = 0; mi < 4; ++mi)
#pragma unroll
      for (int ni = 0; ni < 2; ++ni)
        acc[mi][ni] = __builtin_amdgcn_mfma_f32_16x16x32_bf16(a[mi], b[ni], acc[mi][ni], 0, 0, 0);
  }
#pragma unroll
  for (int ni = 0; ni < 2; ++ni) {
    const int n = wn + ni * 16 + lr;
    const float bias = bf1[n];
#pragma unroll
    for (int mi = 0; mi < 4; ++mi)
#pragma unroll
      for (int rr = 0; rr < 4; ++rr) {
        const int row = mi * 16 + lk * 4 + rr;
        const float h = acc[mi][ni][rr] + bias;
        Hf[(size_t)(m0 + row) * FFN_H + n] = __float2bfloat16(h > 0.f ? h : 0.f);
      }
  }
}

// ---------------- mol FFN layer 2: [8000 x 256] @ [256 x 12], Wf2 in LDS, uint4 Hf loads ----------------
__global__ __launch_bounds__(192)
void molffn2_kernel(const bf16* __restrict__ Hf,
                    const float* __restrict__ Wf2,
                    const float* __restrict__ bias2,
                    float* __restrict__ out) {
  __shared__ float Ws[FFN_H * TASKS];   // 12 KB
  const int tid = threadIdx.x;          // 192 = 16 mols x 12 tasks
  for (int i = tid; i < FFN_H * TASKS; i += 192) Ws[i] = Wf2[i];
  __syncthreads();
  const int m = blockIdx.x * 16 + tid / TASKS;
  const int t = tid % TASKS;
  float s = bias2[t];
  for (int k8 = 0; k8 < FFN_H / 8; ++k8) {
    const uint4 u = *(const uint4*)&Hf[(size_t)m * FFN_H + k8 * 8];
    const float h[8] = { blo(u.x), bhi(u.x), blo(u.y), bhi(u.y),
                         blo(u.z), bhi(u.z), blo(u.w), bhi(u.w) };
#pragma unroll
    for (int e = 0; e < 8; ++e) s += h[e] * Ws[(k8 * 8 + e) * TASKS + t];
  }
  out[(size_t)m * TASKS + t] = s;
}

extern "C" void kernel_launch(void* const* d_in, const int* in_sizes, int n_in,
                              void* d_out, int out_size, void* d_ws, size_t ws_size,
                              hipStream_t stream) {
  const float* atom_output = (const float*)d_in[0];
  const float* f_atoms     = (const float*)d_in[1];
  const float* features    = (const float*)d_in[2];
  const int*   a2a         = (const int*)d_in[3];
  const int*   a_scope     = (const int*)d_in[4];
  const float* W1   = (const float*)d_in[5];
  const float* b1   = (const float*)d_in[6];
  const float* W2   = (const float*)d_in[7];
  const float* b2   = (const float*)d_in[8];
  const float* gamma = (const float*)d_in[9];
  const float* beta  = (const float*)d_in[10];
  const float* Wf1  = (const float*)d_in[11];
  const float* bf1  = (const float*)d_in[12];
  const float* Wf2  = (const float*)d_in[13];
  const float* bf2v = (const float*)d_in[14];
  float* out = (float*)d_out;

  char* ws = (char*)d_ws;
  size_t off = 0;
  bf16* W1bT  = (bf16*)(ws + off); off += (size_t)DFF * K1P * 2;     // 294912
  bf16* W2bT  = (bf16*)(ws + off); off += (size_t)HID * DFF * 2;     // 131072
  bf16* Wf1bT = (bf16*)(ws + off); off += (size_t)FFN_H * K3 * 2;    // 180224
  bf16* atom_emb = (bf16*)(ws + off); off += (size_t)N_ATOMS * HID * 2; // 51.2 MB
  bf16* mol_cat  = (bf16*)(ws + off); off += (size_t)N_MOLS * K3 * 2;   // 5.6 MB
  bf16* Hf       = (bf16*)(ws + off); off += (size_t)N_MOLS * FFN_H * 2;// 4.1 MB
  bf16* ao16     = (bf16*)(ws + off); off += (size_t)N_ATOMS * HID * 2; // 51.2 MB
  // aggr aliases atom_emb: atoms_kernel reads its tile's aggr rows (into LDS,
  // drained at first barrier) strictly before writing the same rows at the end.
  bf16* aggr = atom_emb;

  hipLaunchKernelGGL(prep_weights_kernel, dim3(1184), dim3(256), 0, stream,
                     W1, W2, Wf1, W1bT, W2bT, Wf1bT);
  hipLaunchKernelGGL(conv_ao_kernel, dim3(N_ATOMS * HID / 8 / 256), dim3(256), 0, stream,
                     atom_output, ao16);
  hipLaunchKernelGGL(gather_kernel, dim3(N_ATOMS * 16 / 256), dim3(256), 0, stream,
                     ao16, a2a, aggr);
  hipLaunchKernelGGL(atoms_kernel, dim3(N_ATOMS / MT), dim3(512), 0, stream,
                     aggr, f_atoms,
                     W1bT, b1, W2bT, b2, gamma, beta, atom_emb);
  hipLaunchKernelGGL(mol_kernel, dim3(N_MOLS / 16), dim3(256), 0, stream,
                     atom_emb, features, a_scope, mol_cat);
  hipLaunchKernelGGL(molffn1_kernel, dim3(N_MOLS / 64), dim3(512), 0, stream,
                     mol_cat, Wf1bT, bf1, Hf);
  hipLaunchKernelGGL(molffn2_kernel, dim3(N_MOLS / 16), dim3(192), 0, stream,
                     Hf, Wf2, bf2v, out);
}

// Round 5
// 285.646 us; speedup vs baseline: 1.6603x; 1.3121x over previous
//
#include <hip/hip_runtime.h>
#include <hip/hip_bf16.h>

#define N_ATOMS 200000
#define N_NBR 10
#define N_MOLS 8000
#define HID 128
#define FDIM 151
#define FEAT 200
#define DFF 512
#define FFN_H 256
#define TASKS 12
#define KX 279      // FDIM + HID
#define K1P 288     // KX padded to multiple of 32
#define XS 296      // LDS stride (bf16) for X tile (592B rows -> 8-bank/2-way)
#define HSTR 136    // LDS stride (bf16) for H chunk (272B rows)
#define FS 132      // LDS stride (f32) for pre-LN tile
#define KM 328      // HID + FEAT
#define K3 352      // KM padded to multiple of 32
#define MS 360      // LDS stride for molcat tile
#define MT 80       // atoms kernel M-tile  (2500 tiles exactly)
#define MI 5        // MT/16
#define NCHUNK 4    // 512 N split into 4 chunks of 128
#define SMEM_ATOMS (MT * XS * 2 + MT * HSTR * 2)   // 47360 + 21760 = 69120 B

typedef __hip_bfloat16 bf16;
typedef __attribute__((ext_vector_type(8))) __bf16 bf16x8;
typedef __attribute__((ext_vector_type(4))) float f32x4;

__device__ __forceinline__ float bf2f(bf16 x) { return __bfloat162float(x); }
__device__ __forceinline__ float blo(unsigned w) { union { unsigned u; float f; } c; c.u = w << 16; return c.f; }
__device__ __forceinline__ float bhi(unsigned w) { union { unsigned u; float f; } c; c.u = w & 0xFFFF0000u; return c.f; }

// ---------------- weight prep: transpose + bf16 + K-pad (X layout: [aggr | f_atoms]) ----------------
__global__ void prep_weights_kernel(const float* __restrict__ W1,
                                    const float* __restrict__ W2,
                                    const float* __restrict__ Wf1,
                                    bf16* __restrict__ W1bT,
                                    bf16* __restrict__ W2bT,
                                    bf16* __restrict__ Wf1bT) {
  int idx = blockIdx.x * 256 + threadIdx.x;
  if (idx < DFF * K1P) {                       // W1bT[n][k'], 512x288; k'<128 -> aggr, else f_atoms
    int n = idx / K1P, k = idx - n * K1P;
    float v;
    if (k < HID)      v = W1[(size_t)(FDIM + k) * DFF + n];
    else if (k < KX)  v = W1[(size_t)(k - HID) * DFF + n];
    else              v = 0.f;
    W1bT[idx] = __float2bfloat16(v);
    return;
  }
  idx -= DFF * K1P;
  if (idx < HID * DFF) {                       // W2bT[n][k] = W2[k][n], 128x512
    int n = idx / DFF, k = idx - n * DFF;
    W2bT[idx] = __float2bfloat16(W2[(size_t)k * HID + n]);
    return;
  }
  idx -= HID * DFF;
  if (idx < FFN_H * K3) {                      // Wf1bT[n][k] = Wf1[k][n], 256x352
    int n = idx / K3, k = idx - n * K3;
    float v = (k < KM) ? Wf1[(size_t)k * FFN_H + n] : 0.f;
    Wf1bT[idx] = __float2bfloat16(v);
  }
}

// ---------------- atom_output f32 -> bf16 (halves gather traffic) ----------------
__global__ void conv_ao_kernel(const float* __restrict__ ao, bf16* __restrict__ ao16) {
  const int idx = blockIdx.x * 256 + threadIdx.x;   // exactly N_ATOMS*HID/8 threads
  const float4 v0 = *(const float4*)&ao[(size_t)idx * 8];
  const float4 v1 = *(const float4*)&ao[(size_t)idx * 8 + 4];
  union { bf16 h[8]; uint4 u; } pk;
  pk.h[0] = __float2bfloat16(v0.x); pk.h[1] = __float2bfloat16(v0.y);
  pk.h[2] = __float2bfloat16(v0.z); pk.h[3] = __float2bfloat16(v0.w);
  pk.h[4] = __float2bfloat16(v1.x); pk.h[5] = __float2bfloat16(v1.y);
  pk.h[6] = __float2bfloat16(v1.z); pk.h[7] = __float2bfloat16(v1.w);
  *(uint4*)&ao16[(size_t)idx * 8] = pk.u;
}

// ---------------- standalone neighbor gather-sum: no LDS, no barriers, max occupancy ----------------
__global__ __launch_bounds__(256)
void gather_kernel(const bf16* __restrict__ ao16,
                   const int* __restrict__ a2a,
                   bf16* __restrict__ aggr) {
  const int gid = blockIdx.x * 256 + threadIdx.x;   // exactly N_ATOMS*16 threads
  const int atom = gid >> 4, c8 = gid & 15;
  int idxs[N_NBR];
#pragma unroll
  for (int j = 0; j < N_NBR; ++j) idxs[j] = a2a[atom * N_NBR + j];
  float s[8];
#pragma unroll
  for (int e = 0; e < 8; ++e) s[e] = 0.f;
#pragma unroll
  for (int j = 0; j < N_NBR; ++j) {
    const uint4 u = *(const uint4*)&ao16[(size_t)idxs[j] * HID + c8 * 8];
    s[0] += blo(u.x); s[1] += bhi(u.x);
    s[2] += blo(u.y); s[3] += bhi(u.y);
    s[4] += blo(u.z); s[5] += bhi(u.z);
    s[6] += blo(u.w); s[7] += bhi(u.w);
  }
  union { bf16 h[8]; uint4 u; } pk;
#pragma unroll
  for (int e = 0; e < 8; ++e) pk.h[e] = __float2bfloat16(s[e]);
  *(uint4*)&aggr[(size_t)atom * HID + c8 * 8] = pk.u;
}

// ---------------- fused GEMM1(relu) + GEMM2 + LayerNorm, N-chunked GEMM2 accumulation ----------------
// MT=80 rows/block. LDS: Xs[80][296] bf16 + Hs[80][136] bf16 = 67.5 KB dynamic -> 2 blocks/CU.
// Per N-chunk of 128: GEMM1 chunk -> Hs -> GEMM2 partial accumulates into registers (acc2).
__global__ __launch_bounds__(512, 4)
void atoms_kernel(const bf16* __restrict__ aggr,
                  const float* __restrict__ f_atoms,
                  const bf16* __restrict__ W1bT,
                  const float* __restrict__ b1,
                  const bf16* __restrict__ W2bT,
                  const float* __restrict__ b2,
                  const float* __restrict__ gamma,
                  const float* __restrict__ beta,
                  bf16* __restrict__ atom_emb) {
  extern __shared__ char smem[];
  bf16* Xs = (bf16*)smem;                    // [MT][XS]: cols 0..127 aggr, 128..278 f_atoms, 279..287 zero-pad
  bf16* Hs = (bf16*)(smem + MT * XS * 2);    // [MT][HSTR]: one 128-wide H chunk
  float* Fs = (float*)smem;                  // [MT][FS] f32, overlays Xs (Xs dead after last GEMM1 chunk)

  const int tid = threadIdx.x;
  const int m0 = blockIdx.x * MT;
  const int lane = tid & 63;
  const int w = tid >> 6;
  const int lr = lane & 15;
  const int lk = lane >> 4;

  // hoisted per-lane constants
  const float4 b2v = *(const float4*)&b2[w * 16 + lk * 4];
  const float gam0 = gamma[lane], gam1 = gamma[64 + lane];
  const float bet0 = beta[lane],  bet1 = beta[64 + lane];

  // ---- stage aggr -> Xs[:, 0:128]  (1280 uint4)
  {
    int q = tid;
#pragma unroll
    for (int p = 0; p < 3; ++p) {
      if (p < 2 || q < MT * 16) {
        const int r = q >> 4, c8 = q & 15;
        *(uint4*)&Xs[r * XS + c8 * 8] = *(const uint4*)&aggr[(size_t)(m0 + r) * HID + c8 * 8];
      }
      q += 512;
    }
  }
  // ---- stage f_atoms -> Xs[:, 128:279]  (3020 float4, tile contiguous in HBM)
  {
    const float* fb = &f_atoms[(size_t)m0 * FDIM];
    int q = tid;
#pragma unroll
    for (int p = 0; p < 6; ++p) {
      if (p < 5 || q < (MT * FDIM) / 4) {
        const float4 v = *(const float4*)&fb[q * 4];
        const float vf[4] = { v.x, v.y, v.z, v.w };
        const int flat = q * 4;
        const int r0 = flat / FDIM, c0 = flat - r0 * FDIM;
#pragma unroll
        for (int e = 0; e < 4; ++e) {
          const int cc = c0 + e;
          const int off = (cc < FDIM) ? (r0 * XS + HID + cc) : ((r0 + 1) * XS + HID + cc - FDIM);
          Xs[off] = __float2bfloat16(vf[e]);
        }
      }
      q += 512;
    }
  }
  // ---- zero K-pad cols 279..287 (720 elems)
  {
    int q = tid;
#pragma unroll
    for (int p = 0; p < 2; ++p) {
      if (q < MT * (K1P - KX)) {
        const int r = q / (K1P - KX), cc = q - r * (K1P - KX);
        Xs[r * XS + KX + cc] = __float2bfloat16(0.f);
      }
      q += 512;
    }
  }
  __syncthreads();   // Xs ready

  f32x4 acc2[MI];
#pragma unroll
  for (int mi = 0; mi < MI; ++mi) acc2[mi] = (f32x4)0.f;

#pragma unroll 1
  for (int nc = 0; nc < NCHUNK; ++nc) {
    // ---- GEMM1 chunk: Xs[80 x 288] @ W1[288 x 128chunk] -> relu -> Hs (swapped: D[n][m])
    f32x4 acc1[MI];
#pragma unroll
    for (int mi = 0; mi < MI; ++mi) acc1[mi] = (f32x4)0.f;
    const bf16* w1row = &W1bT[(size_t)(nc * 128 + w * 16 + lr) * K1P + lk * 8];
    __builtin_amdgcn_s_setprio(1);
#pragma unroll
    for (int kk = 0; kk < K1P / 32; ++kk) {
      const bf16x8 b = *(const bf16x8*)&w1row[kk * 32];
#pragma unroll
      for (int mi = 0; mi < MI; ++mi) {
        const bf16x8 a = *(const bf16x8*)&Xs[(mi * 16 + lr) * XS + kk * 32 + lk * 8];
        acc1[mi] = __builtin_amdgcn_mfma_f32_16x16x32_bf16(b, a, acc1[mi], 0, 0, 0);
      }
    }
    __builtin_amdgcn_s_setprio(0);
    // epilogue: +bias, relu, pack 4 consecutive n -> Hs[m][n-local]
    {
      const float4 bb = *(const float4*)&b1[nc * 128 + w * 16 + lk * 4];
      const float bbf[4] = { bb.x, bb.y, bb.z, bb.w };
      const int nb4 = w * 16 + lk * 4;
#pragma unroll
      for (int mi = 0; mi < MI; ++mi) {
        union { bf16 h[4]; uint2 u2; } pk;
#pragma unroll
        for (int r = 0; r < 4; ++r) {
          const float h = acc1[mi][r] + bbf[r];
          pk.h[r] = __float2bfloat16(h > 0.f ? h : 0.f);
        }
        *(uint2*)&Hs[(mi * 16 + lr) * HSTR + nb4] = pk.u2;
      }
    }
    __syncthreads();   // Hs chunk ready

    // ---- GEMM2 partial: Hs[80 x 128] @ W2[128chunk x 128] accumulated into acc2 (swapped: D[n2][m])
    const bf16* w2row = &W2bT[(size_t)(w * 16 + lr) * DFF + nc * 128 + lk * 8];
    __builtin_amdgcn_s_setprio(1);
#pragma unroll
    for (int kk = 0; kk < 4; ++kk) {
      const bf16x8 b = *(const bf16x8*)&w2row[kk * 32];
#pragma unroll
      for (int mi = 0; mi < MI; ++mi) {
        const bf16x8 a = *(const bf16x8*)&Hs[(mi * 16 + lr) * HSTR + kk * 32 + lk * 8];
        acc2[mi] = __builtin_amdgcn_mfma_f32_16x16x32_bf16(b, a, acc2[mi], 0, 0, 0);
      }
    }
    __builtin_amdgcn_s_setprio(0);
    if (nc < NCHUNK - 1) __syncthreads();   // Hs free for next chunk's writes
  }

  // ---- write pre-LN f32 into Fs (overlays Xs; all Xs reads completed before last Hs-ready barrier)
  {
    const int nb4 = w * 16 + lk * 4;
#pragma unroll
    for (int mi = 0; mi < MI; ++mi) {
      float4 v;
      v.x = acc2[mi][0] + b2v.x;
      v.y = acc2[mi][1] + b2v.y;
      v.z = acc2[mi][2] + b2v.z;
      v.w = acc2[mi][3] + b2v.w;
      *(float4*)&Fs[(mi * 16 + lr) * FS + nb4] = v;
    }
  }
  __syncthreads();   // Fs ready

  // ---- LayerNorm: 10 rows per wave
#pragma unroll
  for (int i = 0; i < MT / 8; ++i) {
    const int row = w * (MT / 8) + i;
    const float x0 = Fs[row * FS + lane];
    const float x1 = Fs[row * FS + 64 + lane];
    float s = x0 + x1;
    float q = x0 * x0 + x1 * x1;
#pragma unroll
    for (int off = 32; off > 0; off >>= 1) {
      s += __shfl_xor(s, off);
      q += __shfl_xor(q, off);
    }
    const float mu = s * (1.f / 128.f);
    const float var = q * (1.f / 128.f) - mu * mu;
    const float rs = rsqrtf(var + 1e-6f);
    const int atom = m0 + row;
    atom_emb[(size_t)atom * HID + lane] =
        __float2bfloat16(gam0 * ((x0 - mu) * rs) + bet0);
    atom_emb[(size_t)atom * HID + 64 + lane] =
        __float2bfloat16(gam1 * ((x1 - mu) * rs) + bet1);
  }
}

// ---------------- segment mean + concat features -> mol_cat bf16 (16 mols/block, vectorized) ----------------
__global__ __launch_bounds__(256)
void mol_kernel(const bf16* __restrict__ atom_emb,
                const float* __restrict__ features,
                const int* __restrict__ a_scope,
                bf16* __restrict__ mol_cat) {
  const int tid = threadIdx.x;
  const int mi = tid >> 4, c8 = tid & 15;
  const int base = blockIdx.x * 16;
  const int m = base + mi;
  const int start = a_scope[2 * m];
  const int size  = a_scope[2 * m + 1];
  float s[8];
#pragma unroll
  for (int e = 0; e < 8; ++e) s[e] = 0.f;
  for (int a = 0; a < size; ++a) {
    const uint4 u = *(const uint4*)&atom_emb[(size_t)(start + a) * HID + c8 * 8];
    s[0] += blo(u.x); s[1] += bhi(u.x);
    s[2] += blo(u.y); s[3] += bhi(u.y);
    s[4] += blo(u.z); s[5] += bhi(u.z);
    s[6] += blo(u.w); s[7] += bhi(u.w);
  }
  const float inv = 1.f / (float)size;
  union { bf16 h[8]; uint4 u; } pk;
#pragma unroll
  for (int e = 0; e < 8; ++e) pk.h[e] = __float2bfloat16(s[e] * inv);
  *(uint4*)&mol_cat[(size_t)m * K3 + c8 * 8] = pk.u;
  // features f32 -> bf16 (50 float4 per mol)
  for (int q = tid; q < 16 * 50; q += 256) {
    const int mm = q / 50, qq = q - mm * 50;
    const float4 v = *(const float4*)&features[(size_t)(base + mm) * FEAT + qq * 4];
    union { bf16 h[4]; uint2 u2; } pf;
    pf.h[0] = __float2bfloat16(v.x); pf.h[1] = __float2bfloat16(v.y);
    pf.h[2] = __float2bfloat16(v.z); pf.h[3] = __float2bfloat16(v.w);
    *(uint2*)&mol_cat[(size_t)(base + mm) * K3 + HID + qq * 4] = pf.u2;
  }
  // zero pad cols 328..351
  for (int q = tid; q < 16 * (K3 - KM); q += 256) {
    const int mm = q / (K3 - KM), qq = q - mm * (K3 - KM);
    mol_cat[(size_t)(base + mm) * K3 + KM + qq] = __float2bfloat16(0.f);
  }
}

// ---------------- mol FFN layer 1: [8000 x 352] @ [352 x 256] relu ----------------
__global__ __launch_bounds__(512)
void molffn1_kernel(const bf16* __restrict__ mol_cat,
                    const bf16* __restrict__ Wf1bT,
                    const float* __restrict__ bf1,
                    bf16* __restrict__ Hf) {
  __shared__ bf16 As[64 * MS];   // 45 KB
  const int tid = threadIdx.x;
  const int m0 = blockIdx.x * 64;
  for (int idx = tid; idx < 64 * (K3 / 8); idx += 512) {
    int rr = idx / (K3 / 8), qv = idx - rr * (K3 / 8);
    *(uint4*)&As[rr * MS + qv * 8] = *(const uint4*)&mol_cat[(size_t)(m0 + rr) * K3 + qv * 8];
  }
  __syncthreads();
  const int lane = tid & 63, w = tid >> 6;
  const int lr = lane & 15, lk = lane >> 4;
  const int wn = w * 32;
  f32x4 acc[4][2];
#pragma unroll
  for (int mi = 0; mi < 4; ++mi)
#pragma unroll
    for (int ni = 0; ni < 2; ++ni) acc[mi][ni] = (f32x4)0.f;
#pragma unroll 3
  for (int kk = 0; kk < K3 / 32; ++kk) {
    bf16x8 a[4], b[2];
#pragma unroll
    for (int mi = 0; mi < 4; ++mi)
      a[mi] = *(const bf16x8*)&As[(mi * 16 + lr) * MS + kk * 32 + lk * 8];
#pragma unroll
    for (int ni = 0; ni < 2; ++ni)
      b[ni] = *(const bf16x8*)&Wf1bT[(size_t)(wn + ni * 16 + lr) * K3 + kk * 32 + lk * 8];
#pragma unroll
    for (int mi = 0; mi < 4; ++mi)
#pragma unroll
      for (int ni = 0; ni < 2; ++ni)
        acc[mi][ni] = __builtin_amdgcn_mfma_f32_16x16x32_bf16(a[mi], b[ni], acc[mi][ni], 0, 0, 0);
  }
#pragma unroll
  for (int ni = 0; ni < 2; ++ni) {
    const int n = wn + ni * 16 + lr;
    const float bias = bf1[n];
#pragma unroll
    for (int mi = 0; mi < 4; ++mi)
#pragma unroll
      for (int rr = 0; rr < 4; ++rr) {
        const int row = mi * 16 + lk * 4 + rr;
        const float h = acc[mi][ni][rr] + bias;
        Hf[(size_t)(m0 + row) * FFN_H + n] = __float2bfloat16(h > 0.f ? h : 0.f);
      }
  }
}

// ---------------- mol FFN layer 2: [8000 x 256] @ [256 x 12], Wf2 in LDS, uint4 Hf loads ----------------
__global__ __launch_bounds__(192)
void molffn2_kernel(const bf16* __restrict__ Hf,
                    const float* __restrict__ Wf2,
                    const float* __restrict__ bias2,
                    float* __restrict__ out) {
  __shared__ float Ws[FFN_H * TASKS];   // 12 KB
  const int tid = threadIdx.x;          // 192 = 16 mols x 12 tasks
  for (int i = tid; i < FFN_H * TASKS; i += 192) Ws[i] = Wf2[i];
  __syncthreads();
  const int m = blockIdx.x * 16 + tid / TASKS;
  const int t = tid % TASKS;
  float s = bias2[t];
  for (int k8 = 0; k8 < FFN_H / 8; ++k8) {
    const uint4 u = *(const uint4*)&Hf[(size_t)m * FFN_H + k8 * 8];
    const float h[8] = { blo(u.x), bhi(u.x), blo(u.y), bhi(u.y),
                         blo(u.z), bhi(u.z), blo(u.w), bhi(u.w) };
#pragma unroll
    for (int e = 0; e < 8; ++e) s += h[e] * Ws[(k8 * 8 + e) * TASKS + t];
  }
  out[(size_t)m * TASKS + t] = s;
}

extern "C" void kernel_launch(void* const* d_in, const int* in_sizes, int n_in,
                              void* d_out, int out_size, void* d_ws, size_t ws_size,
                              hipStream_t stream) {
  const float* atom_output = (const float*)d_in[0];
  const float* f_atoms     = (const float*)d_in[1];
  const float* features    = (const float*)d_in[2];
  const int*   a2a         = (const int*)d_in[3];
  const int*   a_scope     = (const int*)d_in[4];
  const float* W1   = (const float*)d_in[5];
  const float* b1   = (const float*)d_in[6];
  const float* W2   = (const float*)d_in[7];
  const float* b2   = (const float*)d_in[8];
  const float* gamma = (const float*)d_in[9];
  const float* beta  = (const float*)d_in[10];
  const float* Wf1  = (const float*)d_in[11];
  const float* bf1  = (const float*)d_in[12];
  const float* Wf2  = (const float*)d_in[13];
  const float* bf2v = (const float*)d_in[14];
  float* out = (float*)d_out;

  char* ws = (char*)d_ws;
  size_t off = 0;
  bf16* W1bT  = (bf16*)(ws + off); off += (size_t)DFF * K1P * 2;     // 294912
  bf16* W2bT  = (bf16*)(ws + off); off += (size_t)HID * DFF * 2;     // 131072
  bf16* Wf1bT = (bf16*)(ws + off); off += (size_t)FFN_H * K3 * 2;    // 180224
  bf16* atom_emb = (bf16*)(ws + off); off += (size_t)N_ATOMS * HID * 2; // 51.2 MB
  bf16* mol_cat  = (bf16*)(ws + off); off += (size_t)N_MOLS * K3 * 2;   // 5.6 MB
  bf16* Hf       = (bf16*)(ws + off); off += (size_t)N_MOLS * FFN_H * 2;// 4.1 MB
  bf16* ao16     = (bf16*)(ws + off); off += (size_t)N_ATOMS * HID * 2; // 51.2 MB
  // aggr aliases atom_emb: atoms_kernel reads its tile's aggr rows into LDS
  // (drained at first barrier) strictly before writing the same rows at the end.
  bf16* aggr = atom_emb;

  // allow 67.5 KB dynamic LDS for atoms_kernel (2 blocks/CU on 160 KB)
  static int smem_set = 0;
  (void)smem_set;
  hipFuncSetAttribute((const void*)atoms_kernel,
                      hipFuncAttributeMaxDynamicSharedMemorySize, SMEM_ATOMS);

  hipLaunchKernelGGL(prep_weights_kernel, dim3(1184), dim3(256), 0, stream,
                     W1, W2, Wf1, W1bT, W2bT, Wf1bT);
  hipLaunchKernelGGL(conv_ao_kernel, dim3(N_ATOMS * HID / 8 / 256), dim3(256), 0, stream,
                     atom_output, ao16);
  hipLaunchKernelGGL(gather_kernel, dim3(N_ATOMS * 16 / 256), dim3(256), 0, stream,
                     ao16, a2a, aggr);
  hipLaunchKernelGGL(atoms_kernel, dim3(N_ATOMS / MT), dim3(512), SMEM_ATOMS, stream,
                     aggr, f_atoms,
                     W1bT, b1, W2bT, b2, gamma, beta, atom_emb);
  hipLaunchKernelGGL(mol_kernel, dim3(N_MOLS / 16), dim3(256), 0, stream,
                     atom_emb, features, a_scope, mol_cat);
  hipLaunchKernelGGL(molffn1_kernel, dim3(N_MOLS / 64), dim3(512), 0, stream,
                     mol_cat, Wf1bT, bf1, Hf);
  hipLaunchKernelGGL(molffn2_kernel, dim3(N_MOLS / 16), dim3(192), 0, stream,
                     Hf, Wf2, bf2v, out);
}